// Round 2
// baseline (346.240 us; speedup 1.0000x reference)
//
#include <hip/hip_runtime.h>

// Output layout (f32 elements), concatenated in reference return order:
//   w_dist  (128,256,1024) @ 0
//   idx     (128,256,1)    @ 33554432   (written as float)
//   w_recon (128,4096)     @ 33587200
//   mu      (128,512)      @ 34111488
//   log_var (128,512)      @ 34177024
#define OFF_WDIST 0
#define OFF_IDX   33554432
#define OFF_WREC  33587200
#define OFF_MU    34111488
#define OFF_LV    34177024

__device__ __forceinline__ float dot16(const float4* a, const float4* b) {
    float s = 0.f;
#pragma unroll
    for (int i = 0; i < 4; ++i) {
        s = fmaf(a[i].x, b[i].x, s);
        s = fmaf(a[i].y, b[i].y, s);
        s = fmaf(a[i].z, b[i].z, s);
        s = fmaf(a[i].w, b[i].w, s);
    }
    return s;
}

// ---------------------------------------------------------------------------
// Init: seed h region with b_enc and w_recon region with b_dec (atomic bases).
// total = 65536 (mu) + 65536 (lv) + 524288 (w_recon) = 655360 elements.
// ---------------------------------------------------------------------------
__global__ __launch_bounds__(256) void init_bias_kernel(float* __restrict__ out,
                                                        const float* __restrict__ b_enc,
                                                        const float* __restrict__ b_dec) {
    int i = blockIdx.x * 256 + threadIdx.x;
    if (i < 65536) {
        out[OFF_MU + i] = b_enc[i & 511];
    } else if (i < 131072) {
        int m = i - 65536;
        out[OFF_LV + m] = b_enc[512 + (m & 511)];
    } else {
        int m = i - 131072;
        out[OFF_WREC + m] = b_dec[m & 4095];
    }
}

// ---------------------------------------------------------------------------
// Encoder GEMM (split-K atomic): h[b][j] += sum_i x[b][i] * W_enc[i][j]
// K-chunk kc covers i = kc*256 + dc  (fixed e = kc), x[b][i] = w_q[b][dc*16+kc]
// grid = 256 blocks: jt (16 tiles of 64 cols) x kc (16 chunks of 256)
// block = 256 thr; thread tile = 8 rows x 4 cols; LDS staged, XOR-swizzled xs.
// ---------------------------------------------------------------------------
__global__ __launch_bounds__(256) void enc_gemm_kernel(const float* __restrict__ w_q,
                                                       const float* __restrict__ W_enc,
                                                       float* __restrict__ mu_out,
                                                       float* __restrict__ lv_out) {
    __shared__ float xs[128 * 32];
    __shared__ float ws[32 * 64];
    const int tid = threadIdx.x;
    const int jt = blockIdx.x & 15;
    const int kc = blockIdx.x >> 4;
    const int cbase = jt * 64;
    const int tx = tid & 15;   // col group (4 cols)
    const int ty = tid >> 4;   // row group (8 rows)

    float acc[8][4];
#pragma unroll
    for (int r = 0; r < 8; ++r)
#pragma unroll
        for (int c = 0; c < 4; ++c) acc[r][c] = 0.f;

    const int lb = tid >> 1;             // xs load: row
    const int libase = (tid & 1) * 16;   // xs load: ii base
    const int wj = tid & 63;             // ws load: col
    const int wi0 = (tid >> 6) * 8;      // ws load: row base

    for (int sub = 0; sub < 8; ++sub) {
        const int dc0 = sub * 32;
        // stage xs[b][ii] = w_q[b][(dc0+ii)*16 + kc], XOR-swizzle groups of 4
        {
            const float* src = w_q + lb * 4096 + kc;
#pragma unroll
            for (int l = 0; l < 16; ++l) {
                int ii = libase + l;
                float v = src[(dc0 + ii) << 4];
                int pos = lb * 32 + (ii & 3) + ((((ii >> 2) ^ ((lb >> 3) & 7))) << 2);
                xs[pos] = v;
            }
        }
        // stage ws[ii][jj] = W_enc[(kc*256 + dc0 + ii)*1024 + cbase + jj]
        {
#pragma unroll
            for (int l = 0; l < 8; ++l) {
                int ii = wi0 + l;
                ws[ii * 64 + wj] = W_enc[(kc * 256 + dc0 + ii) * 1024 + cbase + wj];
            }
        }
        __syncthreads();
#pragma unroll
        for (int g = 0; g < 8; ++g) {
            float4 wv[4];
#pragma unroll
            for (int q = 0; q < 4; ++q)
                wv[q] = *(const float4*)&ws[(g * 4 + q) * 64 + tx * 4];
#pragma unroll
            for (int r = 0; r < 8; ++r) {
                const int b = ty * 8 + r;
                float4 xv = *(const float4*)&xs[b * 32 + ((g ^ (ty & 7)) << 2)];
                const float xq[4] = {xv.x, xv.y, xv.z, xv.w};
#pragma unroll
                for (int q = 0; q < 4; ++q) {
                    acc[r][0] = fmaf(xq[q], wv[q].x, acc[r][0]);
                    acc[r][1] = fmaf(xq[q], wv[q].y, acc[r][1]);
                    acc[r][2] = fmaf(xq[q], wv[q].z, acc[r][2]);
                    acc[r][3] = fmaf(xq[q], wv[q].w, acc[r][3]);
                }
            }
        }
        __syncthreads();
    }

    // scatter: j < 512 -> mu, else log_var  (uniform per block: cbase multiple of 64)
#pragma unroll
    for (int r = 0; r < 8; ++r) {
        const int b = ty * 8 + r;
#pragma unroll
        for (int c = 0; c < 4; ++c) {
            const int j = cbase + tx * 4 + c;
            if (j < 512) atomicAdd(mu_out + b * 512 + j, acc[r][c]);
            else         atomicAdd(lv_out + b * 512 + (j - 512), acc[r][c]);
        }
    }
}

// ---------------------------------------------------------------------------
// Decoder GEMM (split-K atomic): w_recon[b][c] += sum_i mu[b][i]*W_dec[i][c]
// grid = 256: ct (64 tiles of 64 cols) x kc (4 chunks of 128)
// ---------------------------------------------------------------------------
__global__ __launch_bounds__(256) void dec_gemm_kernel(const float* __restrict__ mu_in,
                                                       const float* __restrict__ W_dec,
                                                       float* __restrict__ wrec_out) {
    __shared__ float xs[128 * 32];
    __shared__ float ws[32 * 64];
    const int tid = threadIdx.x;
    const int ct = blockIdx.x >> 2;
    const int kc = blockIdx.x & 3;
    const int cbase = ct * 64;
    const int tx = tid & 15;
    const int ty = tid >> 4;

    float acc[8][4];
#pragma unroll
    for (int r = 0; r < 8; ++r)
#pragma unroll
        for (int c = 0; c < 4; ++c) acc[r][c] = 0.f;

    const int lb = tid >> 1;
    const int libase = (tid & 1) * 16;
    const int wj = tid & 63;
    const int wi0 = (tid >> 6) * 8;

    for (int sub = 0; sub < 4; ++sub) {
        const int i0 = kc * 128 + sub * 32;
        {
            const float* src = mu_in + lb * 512 + i0;
#pragma unroll
            for (int l = 0; l < 16; ++l) {
                int ii = libase + l;
                float v = src[ii];
                int pos = lb * 32 + (ii & 3) + ((((ii >> 2) ^ ((lb >> 3) & 7))) << 2);
                xs[pos] = v;
            }
        }
        {
#pragma unroll
            for (int l = 0; l < 8; ++l) {
                int ii = wi0 + l;
                ws[ii * 64 + wj] = W_dec[(i0 + ii) * 4096 + cbase + wj];
            }
        }
        __syncthreads();
#pragma unroll
        for (int g = 0; g < 8; ++g) {
            float4 wv[4];
#pragma unroll
            for (int q = 0; q < 4; ++q)
                wv[q] = *(const float4*)&ws[(g * 4 + q) * 64 + tx * 4];
#pragma unroll
            for (int r = 0; r < 8; ++r) {
                const int b = ty * 8 + r;
                float4 xv = *(const float4*)&xs[b * 32 + ((g ^ (ty & 7)) << 2)];
                const float xq[4] = {xv.x, xv.y, xv.z, xv.w};
#pragma unroll
                for (int q = 0; q < 4; ++q) {
                    acc[r][0] = fmaf(xq[q], wv[q].x, acc[r][0]);
                    acc[r][1] = fmaf(xq[q], wv[q].y, acc[r][1]);
                    acc[r][2] = fmaf(xq[q], wv[q].z, acc[r][2]);
                    acc[r][3] = fmaf(xq[q], wv[q].w, acc[r][3]);
                }
            }
        }
        __syncthreads();
    }

#pragma unroll
    for (int r = 0; r < 8; ++r) {
        const int b = ty * 8 + r;
#pragma unroll
        for (int c = 0; c < 4; ++c) {
            atomicAdd(wrec_out + b * 4096 + cbase + tx * 4 + c, acc[r][c]);
        }
    }
}

// ---------------------------------------------------------------------------
// Distances + argmin.
// grid = 4096: dc (256) x bg (16 groups of 8 batch rows). block = 256 thr.
// thread t handles k = 4t..4t+3 (float4 store); 8 rows per block reuse cb row.
// argmin: first-occurrence tie-break (index) via wave shuffle + LDS combine.
// ---------------------------------------------------------------------------
__global__ __launch_bounds__(256) void dist_kernel(const float* __restrict__ wrec,
                                                   const float* __restrict__ cbk,
                                                   float* __restrict__ wdist,
                                                   float* __restrict__ idx_out) {
    const int dc = blockIdx.x & 255;
    const int bg = blockIdx.x >> 8;
    const int t = threadIdx.x;

    float4 xr[8][4];
    float x2[8];
#pragma unroll
    for (int r = 0; r < 8; ++r) {
        const float4* p = (const float4*)(wrec + (bg * 8 + r) * 4096 + dc * 16);
        xr[r][0] = p[0]; xr[r][1] = p[1]; xr[r][2] = p[2]; xr[r][3] = p[3];
        x2[r] = dot16(xr[r], xr[r]);
    }

    const float* cbp = cbk + (size_t)dc * 1024 * 16;
    float dv[8][4];
    float minv[8];
    int mink[8];
#pragma unroll
    for (int r = 0; r < 8; ++r) { minv[r] = 3.4e38f; mink[r] = 0; }

    const int k0 = t * 4;
#pragma unroll
    for (int kk = 0; kk < 4; ++kk) {
        const int k = k0 + kk;
        const float4* cp = (const float4*)(cbp + (size_t)k * 16);
        float4 cv[4];
        cv[0] = cp[0]; cv[1] = cp[1]; cv[2] = cp[2]; cv[3] = cp[3];
        const float cc = dot16(cv, cv);
#pragma unroll
        for (int r = 0; r < 8; ++r) {
            const float cr = dot16(xr[r], cv);
            const float dd = (x2[r] - 2.f * cr) + cc;
            dv[r][kk] = dd;
            if (dd < minv[r]) { minv[r] = dd; mink[r] = k; }
        }
    }

#pragma unroll
    for (int r = 0; r < 8; ++r) {
        float4 o = make_float4(dv[r][0], dv[r][1], dv[r][2], dv[r][3]);
        *(float4*)(wdist + (size_t)((bg * 8 + r) * 256 + dc) * 1024 + k0) = o;
    }

    __shared__ float rvs[8][4];
    __shared__ int rks[8][4];
    const int lane = t & 63;
    const int wv = t >> 6;
#pragma unroll
    for (int r = 0; r < 8; ++r) {
        float v = minv[r];
        int k = mink[r];
#pragma unroll
        for (int off = 32; off > 0; off >>= 1) {
            float ov = __shfl_down(v, off);
            int ok = __shfl_down(k, off);
            if (ov < v || (ov == v && ok < k)) { v = ov; k = ok; }
        }
        if (lane == 0) { rvs[r][wv] = v; rks[r][wv] = k; }
    }
    __syncthreads();
    if (t < 8) {
        float v = rvs[t][0];
        int k = rks[t][0];
#pragma unroll
        for (int w = 1; w < 4; ++w) {
            float ov = rvs[t][w];
            int ok = rks[t][w];
            if (ov < v || (ov == v && ok < k)) { v = ov; k = ok; }
        }
        idx_out[(bg * 8 + t) * 256 + dc] = (float)k;
    }
}

extern "C" void kernel_launch(void* const* d_in, const int* in_sizes, int n_in,
                              void* d_out, int out_size, void* d_ws, size_t ws_size,
                              hipStream_t stream) {
    const float* w_q   = (const float*)d_in[0];
    // d_in[1] = pseudo_inputs: unused (pseudo rows of h are discarded)
    const float* W_enc = (const float*)d_in[2];
    const float* b_enc = (const float*)d_in[3];
    const float* W_dec = (const float*)d_in[4];
    const float* b_dec = (const float*)d_in[5];
    const float* cbk   = (const float*)d_in[6];
    float* out = (float*)d_out;

    float* mu_out = out + OFF_MU;
    float* lv_out = out + OFF_LV;
    float* wrec   = out + OFF_WREC;
    float* wdist  = out + OFF_WDIST;
    float* idx_o  = out + OFF_IDX;

    // 655360 elements / 256 = 2560 blocks
    hipLaunchKernelGGL(init_bias_kernel, dim3(2560), dim3(256), 0, stream, out, b_enc, b_dec);
    hipLaunchKernelGGL(enc_gemm_kernel, dim3(256), dim3(256), 0, stream, w_q, W_enc, mu_out, lv_out);
    hipLaunchKernelGGL(dec_gemm_kernel, dim3(256), dim3(256), 0, stream, mu_out, W_dec, wrec);
    hipLaunchKernelGGL(dist_kernel, dim3(4096), dim3(256), 0, stream, wrec, cbk, wdist, idx_o);
}

// Round 3
// 259.954 us; speedup vs baseline: 1.3319x; 1.3319x over previous
//
#include <hip/hip_runtime.h>

// Output layout (f32 elements), concatenated in reference return order:
//   w_dist  (128,256,1024) @ 0          (used as partial-sum scratch before dist)
//   idx     (128,256,1)    @ 33554432   (written as float)
//   w_recon (128,4096)     @ 33587200
//   mu      (128,512)      @ 34111488
//   log_var (128,512)      @ 34177024
#define OFF_WDIST 0
#define OFF_IDX   33554432
#define OFF_WREC  33587200
#define OFF_MU    34111488
#define OFF_LV    34177024

__device__ __forceinline__ float dot16(const float4* a, const float4* b) {
    float s = 0.f;
#pragma unroll
    for (int i = 0; i < 4; ++i) {
        s = fmaf(a[i].x, b[i].x, s);
        s = fmaf(a[i].y, b[i].y, s);
        s = fmaf(a[i].z, b[i].z, s);
        s = fmaf(a[i].w, b[i].w, s);
    }
    return s;
}

// ---------------------------------------------------------------------------
// Encoder GEMM stage 1 (split-K partials, no atomics).
// h[b][j] = sum_i x[b][i]*W_enc[i][j];  x[b][e*256+dc] = w_q[b][dc*16+e].
// K-chunk kc covers w_q cols [kc*64, kc*64+64)  (dc block of 4 x all 16 e)
//   local l -> global i(l) = (l&15)*256 + kc*4 + (l>>4)
// grid = 512: jt (8 tiles of 128 cols) x kc (64 chunks of 64 K)
// block 256 thr, thread tile 8x8; LDS: xs_t[64][128] + ws[64][128] = 64 KB.
// partials: part[kc][b][j] = out[WDIST] region, 64*128*1024 floats = 32 MB.
// ---------------------------------------------------------------------------
__global__ __launch_bounds__(256) void enc_gemm1_kernel(const float* __restrict__ w_q,
                                                        const float* __restrict__ W_enc,
                                                        float* __restrict__ part) {
    __shared__ float xs_t[64 * 128];  // [l][b]
    __shared__ float ws[64 * 128];    // [l][j]
    const int tid = threadIdx.x;
    const int jt = blockIdx.x & 7;    // 8 col tiles of 128
    const int kc = blockIdx.x >> 3;   // 64 K-chunks

    // stage xs_t: coalesced float4 from w_q, transposed scalar writes to LDS
    {
        const int b = tid >> 1;
        const int half = tid & 1;
        const float* src = w_q + b * 4096 + kc * 64;
#pragma unroll
        for (int u = 0; u < 8; ++u) {
            const int l0 = half * 32 + u * 4;
            const float4 v = *(const float4*)(src + l0);
            xs_t[(l0 + 0) * 128 + b] = v.x;
            xs_t[(l0 + 1) * 128 + b] = v.y;
            xs_t[(l0 + 2) * 128 + b] = v.z;
            xs_t[(l0 + 3) * 128 + b] = v.w;
        }
    }
    // stage ws: row gi(l), coalesced float4
    {
        const int l = tid >> 2;
        const int q = tid & 3;
        const int gi = (l & 15) * 256 + kc * 4 + (l >> 4);
        const float* src = W_enc + (size_t)gi * 1024 + jt * 128 + q * 32;
        float* dst = &ws[l * 128 + q * 32];
#pragma unroll
        for (int u = 0; u < 8; ++u) {
            *(float4*)(dst + u * 4) = *(const float4*)(src + u * 4);
        }
    }
    __syncthreads();

    const int tx = tid & 15;   // N: cols tx*4 and 64+tx*4
    const int ty = tid >> 4;   // M: rows ty*8..+8
    float acc[8][8];
#pragma unroll
    for (int r = 0; r < 8; ++r)
#pragma unroll
        for (int c = 0; c < 8; ++c) acc[r][c] = 0.f;

    for (int l = 0; l < 64; ++l) {
        const float4 a0 = *(const float4*)&xs_t[l * 128 + ty * 8];
        const float4 a1 = *(const float4*)&xs_t[l * 128 + ty * 8 + 4];
        const float4 w0 = *(const float4*)&ws[l * 128 + tx * 4];
        const float4 w1 = *(const float4*)&ws[l * 128 + 64 + tx * 4];
        const float av[8] = {a0.x, a0.y, a0.z, a0.w, a1.x, a1.y, a1.z, a1.w};
        const float wv[8] = {w0.x, w0.y, w0.z, w0.w, w1.x, w1.y, w1.z, w1.w};
#pragma unroll
        for (int r = 0; r < 8; ++r)
#pragma unroll
            for (int c = 0; c < 8; ++c)
                acc[r][c] = fmaf(av[r], wv[c], acc[r][c]);
    }

    // store partials: part[(kc*128 + b)*1024 + jt*128 + col]
#pragma unroll
    for (int r = 0; r < 8; ++r) {
        const int brow = ty * 8 + r;
        float* dst = part + (size_t)(kc * 128 + brow) * 1024 + jt * 128;
        *(float4*)(dst + tx * 4)      = make_float4(acc[r][0], acc[r][1], acc[r][2], acc[r][3]);
        *(float4*)(dst + 64 + tx * 4) = make_float4(acc[r][4], acc[r][5], acc[r][6], acc[r][7]);
    }
}

// ---------------------------------------------------------------------------
// Encoder reduce: mu/log_var = b_enc + sum over 64 partials.
// grid 512 x 256: one thread per (b,j) scalar output.
// ---------------------------------------------------------------------------
__global__ __launch_bounds__(256) void enc_reduce_kernel(const float* __restrict__ part,
                                                         const float* __restrict__ b_enc,
                                                         float* __restrict__ mu_out,
                                                         float* __restrict__ lv_out) {
    const int g = blockIdx.x * 256 + threadIdx.x;
    const int b = g >> 10;
    const int j = g & 1023;
    float sum = b_enc[j];
#pragma unroll 8
    for (int kc = 0; kc < 64; ++kc) {
        sum += part[(size_t)((kc * 128 + b) << 10) + j];
    }
    if (j < 512) mu_out[b * 512 + j] = sum;
    else         lv_out[b * 512 + (j - 512)] = sum;
}

// ---------------------------------------------------------------------------
// Decoder GEMM stage 1: w_recon partials = mu @ W_dec  (M=128,K=512,N=4096)
// grid = 512: ct (32 tiles of 128 cols) x kc (16 chunks of 32 K)
// LDS: xs_t[32][128] + ws[32][128] = 32 KB. partials 16*128*4096 = 32 MB.
// ---------------------------------------------------------------------------
__global__ __launch_bounds__(256) void dec_gemm1_kernel(const float* __restrict__ mu_in,
                                                        const float* __restrict__ W_dec,
                                                        float* __restrict__ part) {
    __shared__ float xs_t[32 * 128];  // [l][b]
    __shared__ float ws[32 * 128];    // [l][j]
    const int tid = threadIdx.x;
    const int ct = blockIdx.x & 31;   // 32 col tiles of 128
    const int kc = blockIdx.x >> 5;   // 16 K-chunks of 32

    {
        const int b = tid >> 1;
        const int half = tid & 1;
        const float* src = mu_in + b * 512 + kc * 32;
#pragma unroll
        for (int u = 0; u < 4; ++u) {
            const int l0 = half * 16 + u * 4;
            const float4 v = *(const float4*)(src + l0);
            xs_t[(l0 + 0) * 128 + b] = v.x;
            xs_t[(l0 + 1) * 128 + b] = v.y;
            xs_t[(l0 + 2) * 128 + b] = v.z;
            xs_t[(l0 + 3) * 128 + b] = v.w;
        }
    }
    {
        const int l = tid >> 3;
        const int q = tid & 7;
        const float* src = W_dec + (size_t)(kc * 32 + l) * 4096 + ct * 128 + q * 16;
        float* dst = &ws[l * 128 + q * 16];
#pragma unroll
        for (int u = 0; u < 4; ++u) {
            *(float4*)(dst + u * 4) = *(const float4*)(src + u * 4);
        }
    }
    __syncthreads();

    const int tx = tid & 15;
    const int ty = tid >> 4;
    float acc[8][8];
#pragma unroll
    for (int r = 0; r < 8; ++r)
#pragma unroll
        for (int c = 0; c < 8; ++c) acc[r][c] = 0.f;

    for (int l = 0; l < 32; ++l) {
        const float4 a0 = *(const float4*)&xs_t[l * 128 + ty * 8];
        const float4 a1 = *(const float4*)&xs_t[l * 128 + ty * 8 + 4];
        const float4 w0 = *(const float4*)&ws[l * 128 + tx * 4];
        const float4 w1 = *(const float4*)&ws[l * 128 + 64 + tx * 4];
        const float av[8] = {a0.x, a0.y, a0.z, a0.w, a1.x, a1.y, a1.z, a1.w};
        const float wv[8] = {w0.x, w0.y, w0.z, w0.w, w1.x, w1.y, w1.z, w1.w};
#pragma unroll
        for (int r = 0; r < 8; ++r)
#pragma unroll
            for (int c = 0; c < 8; ++c)
                acc[r][c] = fmaf(av[r], wv[c], acc[r][c]);
    }

#pragma unroll
    for (int r = 0; r < 8; ++r) {
        const int brow = ty * 8 + r;
        float* dst = part + (size_t)(kc * 128 + brow) * 4096 + ct * 128;
        *(float4*)(dst + tx * 4)      = make_float4(acc[r][0], acc[r][1], acc[r][2], acc[r][3]);
        *(float4*)(dst + 64 + tx * 4) = make_float4(acc[r][4], acc[r][5], acc[r][6], acc[r][7]);
    }
}

// ---------------------------------------------------------------------------
// Decoder reduce: w_recon = b_dec + sum over 16 partials.
// grid 2048 x 256: one thread per (b,n) scalar output.
// ---------------------------------------------------------------------------
__global__ __launch_bounds__(256) void dec_reduce_kernel(const float* __restrict__ part,
                                                         const float* __restrict__ b_dec,
                                                         float* __restrict__ wrec_out) {
    const int g = blockIdx.x * 256 + threadIdx.x;
    const int b = g >> 12;
    const int n = g & 4095;
    float sum = b_dec[n];
#pragma unroll
    for (int kc = 0; kc < 16; ++kc) {
        sum += part[(size_t)((kc * 128 + b) << 12) + n];
    }
    wrec_out[b * 4096 + n] = sum;
}

// ---------------------------------------------------------------------------
// Distances + argmin.
// grid = 4096: dc (256) x bg (16 groups of 8 batch rows). block = 256 thr.
// ---------------------------------------------------------------------------
__global__ __launch_bounds__(256) void dist_kernel(const float* __restrict__ wrec,
                                                   const float* __restrict__ cbk,
                                                   float* __restrict__ wdist,
                                                   float* __restrict__ idx_out) {
    const int dc = blockIdx.x & 255;
    const int bg = blockIdx.x >> 8;
    const int t = threadIdx.x;

    float4 xr[8][4];
    float x2[8];
#pragma unroll
    for (int r = 0; r < 8; ++r) {
        const float4* p = (const float4*)(wrec + (bg * 8 + r) * 4096 + dc * 16);
        xr[r][0] = p[0]; xr[r][1] = p[1]; xr[r][2] = p[2]; xr[r][3] = p[3];
        x2[r] = dot16(xr[r], xr[r]);
    }

    const float* cbp = cbk + (size_t)dc * 1024 * 16;
    float dv[8][4];
    float minv[8];
    int mink[8];
#pragma unroll
    for (int r = 0; r < 8; ++r) { minv[r] = 3.4e38f; mink[r] = 0; }

    const int k0 = t * 4;
#pragma unroll
    for (int kk = 0; kk < 4; ++kk) {
        const int k = k0 + kk;
        const float4* cp = (const float4*)(cbp + (size_t)k * 16);
        float4 cv[4];
        cv[0] = cp[0]; cv[1] = cp[1]; cv[2] = cp[2]; cv[3] = cp[3];
        const float cc = dot16(cv, cv);
#pragma unroll
        for (int r = 0; r < 8; ++r) {
            const float cr = dot16(xr[r], cv);
            const float dd = (x2[r] - 2.f * cr) + cc;
            dv[r][kk] = dd;
            if (dd < minv[r]) { minv[r] = dd; mink[r] = k; }
        }
    }

#pragma unroll
    for (int r = 0; r < 8; ++r) {
        float4 o = make_float4(dv[r][0], dv[r][1], dv[r][2], dv[r][3]);
        *(float4*)(wdist + (size_t)((bg * 8 + r) * 256 + dc) * 1024 + k0) = o;
    }

    __shared__ float rvs[8][4];
    __shared__ int rks[8][4];
    const int lane = t & 63;
    const int wv = t >> 6;
#pragma unroll
    for (int r = 0; r < 8; ++r) {
        float v = minv[r];
        int k = mink[r];
#pragma unroll
        for (int off = 32; off > 0; off >>= 1) {
            float ov = __shfl_down(v, off);
            int ok = __shfl_down(k, off);
            if (ov < v || (ov == v && ok < k)) { v = ov; k = ok; }
        }
        if (lane == 0) { rvs[r][wv] = v; rks[r][wv] = k; }
    }
    __syncthreads();
    if (t < 8) {
        float v = rvs[t][0];
        int k = rks[t][0];
#pragma unroll
        for (int w = 1; w < 4; ++w) {
            float ov = rvs[t][w];
            int ok = rks[t][w];
            if (ov < v || (ov == v && ok < k)) { v = ov; k = ok; }
        }
        idx_out[(bg * 8 + t) * 256 + dc] = (float)k;
    }
}

extern "C" void kernel_launch(void* const* d_in, const int* in_sizes, int n_in,
                              void* d_out, int out_size, void* d_ws, size_t ws_size,
                              hipStream_t stream) {
    const float* w_q   = (const float*)d_in[0];
    // d_in[1] = pseudo_inputs: unused (pseudo rows of h are discarded)
    const float* W_enc = (const float*)d_in[2];
    const float* b_enc = (const float*)d_in[3];
    const float* W_dec = (const float*)d_in[4];
    const float* b_dec = (const float*)d_in[5];
    const float* cbk   = (const float*)d_in[6];
    float* out = (float*)d_out;

    float* mu_out = out + OFF_MU;
    float* lv_out = out + OFF_LV;
    float* wrec   = out + OFF_WREC;
    float* wdist  = out + OFF_WDIST;
    float* idx_o  = out + OFF_IDX;
    // split-K partials live in the (not-yet-written) w_dist region: 32 MB max,
    // consumed by each reduce before dist_kernel overwrites the region.
    float* part   = out + OFF_WDIST;

    hipLaunchKernelGGL(enc_gemm1_kernel,  dim3(512),  dim3(256), 0, stream, w_q, W_enc, part);
    hipLaunchKernelGGL(enc_reduce_kernel, dim3(512),  dim3(256), 0, stream, part, b_enc, mu_out, lv_out);
    hipLaunchKernelGGL(dec_gemm1_kernel,  dim3(512),  dim3(256), 0, stream, mu_out, W_dec, part);
    hipLaunchKernelGGL(dec_reduce_kernel, dim3(2048), dim3(256), 0, stream, part, b_dec, wrec);
    hipLaunchKernelGGL(dist_kernel,       dim3(4096), dim3(256), 0, stream, wrec, cbk, wdist, idx_o);
}